// Round 14
// baseline (49.692 us; speedup 1.0000x reference)
//
#include <hip/hip_runtime.h>

typedef __attribute__((ext_vector_type(8))) __bf16 bf16x8;
typedef __attribute__((ext_vector_type(4))) float f32x4;

#define M_ 256
#define N_ 4096
#define K_ 4096
#define SPLITK 4
#define KC (K_ / SPLITK)   // 1024
#define BM 128
#define BN 128
#define BK 32
#define KSTEPS (KC / BK)   // 32

// Tiled operand layout: 1KB bf16 tile = 16 rows x 32 k; tile(rt,kt) index
// rt*128+kt; slot lane = (row&15)+16*((k>>3)&3), elem = k&7.
// Because frag-slot == lane, every MFMA fragment is ONE coalesced 16B/lane
// global load — the GEMM runs entirely from registers (no LDS, no barriers).
// xgh/xgl: 16B/slot bf16. z2: 2B/slot = 8x2-bit lattice indices.

// ---------- helpers ----------

__device__ __forceinline__ unsigned short f2bf(float f) {
  unsigned int u = __builtin_bit_cast(unsigned int, f);
  u += 0x7fffu + ((u >> 16) & 1u);
  return (unsigned short)(u >> 16);
}

__device__ __forceinline__ float lsq1(float y, float a, float s) {
  float yc = fminf(fmaxf(y, -a), a);
  return rintf(yc / s) * s;
}

// decode 8x2-bit word -> 8 bf16 (values idx-2 in {-2,-1,0,1}), ascending elems.
// v_cvt_pk_bf16_f32 on exact small ints == ZLUT bits: -2->0xC000, -1->0xBF80,
// 0->0x0000, 3->0x3F80.  (low 16 = src0 = even elem, matching the staged path.)
__device__ __forceinline__ bf16x8 zdec_pk(unsigned int w) {
  unsigned int d0, d1, d2, d3;
#define ZP(P, D)                                                        \
  {                                                                     \
    const float f0 = (float)((w >> (4 * P)) & 3u) - 2.0f;               \
    const float f1 = (float)((w >> (4 * P + 2)) & 3u) - 2.0f;           \
    asm("v_cvt_pk_bf16_f32 %0, %1, %2" : "=v"(D) : "v"(f0), "v"(f1));   \
  }
  ZP(0, d0) ZP(1, d1) ZP(2, d2) ZP(3, d3)
#undef ZP
  const uint4 u = make_uint4(d0, d1, d2, d3);
  return __builtin_bit_cast(bf16x8, u);
}

// ---------- K1: fused producer (R13 verbatim — verified, DO NOT TOUCH) ----------
// blocks [0, NQB): lattice-quantize W -> z2 (2-bit indices, tiled slot order).
//   z dot: f32 UNFUSED mul+add, sequential ascending, contract(off) — matches
//   XLA:CPU's fmul/fadd chain (contraction was the R1/R9/R10 0.701 bug).
// blocks [NQB, NQB+NXB): xg = x_blocks @ G^T -> bf16 hi/lo (tiled layout).

#define NQB ((N_ * K_ / 8) / 256)  // 8192
#define NXB ((M_ * K_ / 8) / 256)  // 512

__global__ __launch_bounds__(256) void k_prep(const float* __restrict__ W,
                                              const float* __restrict__ theta,
                                              const float* __restrict__ Ginv,
                                              const float* __restrict__ x,
                                              const float* __restrict__ G,
                                              unsigned short* __restrict__ z2,
                                              unsigned short* __restrict__ hi,
                                              unsigned short* __restrict__ lo,
                                              int kTheta) {
  __shared__ float Ms[64];
  const int tid = threadIdx.x;
  const bool isQ = blockIdx.x < NQB;
  if (tid < 64) Ms[tid] = isQ ? Ginv[tid] : G[tid];
  __syncthreads();

  if (isQ) {
#pragma clang fp contract(off)
    const int s = blockIdx.x * 256 + tid;       // output slot
    const int lane6 = s & 63;
    const int tile = s >> 6;
    const int o  = ((tile >> 7) << 4) + (lane6 & 15);   // W row
    const int kb = ((tile & 127) << 2) + (lane6 >> 4);  // 8-elt k-block
    const float4* wp = (const float4*)(W + ((size_t)o << 12) + ((size_t)kb << 3));
    const float4 w0 = wp[0], w1 = wp[1];
    float sc = 0.f;
    for (int t = 0; t < kTheta; ++t) sc += theta[o * kTheta + t];
    sc /= (float)kTheta;
    const float wsv[8] = {w0.x * sc, w0.y * sc, w0.z * sc, w0.w * sc,
                          w1.x * sc, w1.y * sc, w1.z * sc, w1.w * sc};
    unsigned int word = 0u;
#pragma unroll
    for (int i = 0; i < 8; ++i) {
      float t = 0.f;
#pragma unroll
      for (int j = 0; j < 8; ++j)
        t = t + wsv[j] * Ms[j * 8 + i];   // contract(off): separate rn mul + rn add
      const int zi = (int)rintf(t);
      word |= (unsigned int)((zi + 2) & 3) << (2 * i);
    }
    z2[s] = (unsigned short)word;
  } else {
    const int s = (blockIdx.x - NQB) * 256 + tid;
    const int lane6 = s & 63;
    const int tile = s >> 6;
    const int m  = ((tile >> 7) << 4) + (lane6 & 15);
    const int kb = ((tile & 127) << 2) + (lane6 >> 4);
    const float4* xp = (const float4*)(x + ((size_t)m << 12) + ((size_t)kb << 3));
    const float4 a0 = xp[0], a1 = xp[1];
    float xv[8] = {a0.x, a0.y, a0.z, a0.w, a1.x, a1.y, a1.z, a1.w};
    unsigned int ph[4] = {0u, 0u, 0u, 0u}, pl[4] = {0u, 0u, 0u, 0u};
#pragma unroll
    for (int i = 0; i < 8; ++i) {
      float t = 0.f;
#pragma unroll
      for (int j = 0; j < 8; ++j) t = fmaf(xv[j], Ms[i * 8 + j], t);
      const unsigned short hb = f2bf(t);
      const float hf = __builtin_bit_cast(float, (unsigned int)hb << 16);
      const unsigned short lb = f2bf(t - hf);
      ph[i >> 1] |= ((unsigned int)hb) << ((i & 1) * 16);
      pl[i >> 1] |= ((unsigned int)lb) << ((i & 1) * 16);
    }
    *(uint4*)(hi + ((size_t)s << 3)) = make_uint4(ph[0], ph[1], ph[2], ph[3]);
    *(uint4*)(lo + ((size_t)s << 3)) = make_uint4(pl[0], pl[1], pl[2], pl[3]);
  }
}

// ---------- K2: all-register split-K GEMM (no LDS, no barriers) ----------
// 512 thr = 8 waves (4m x 2n), wave = 32x64 out, tile 128x128, BK=32.
// Per step: A frags = 4 direct bf16x8 global loads (xgh/xgl, L2-resident);
// B frags = 4 z2 words -> cvt_pk decode (bit == ZLUT). 2-deep register
// prefetch, compiler-managed waitcnts. b&7 = (mt,sk) -> per-XCD L2 locality.
// Per-accumulator MFMA k-order (ascending k32, hi-then-lo) = verified r3-r13.

__global__ __launch_bounds__(512) void k_gemm(const unsigned short* __restrict__ xgh,
                                              const unsigned short* __restrict__ xgl,
                                              const unsigned short* __restrict__ z2,
                                              float* __restrict__ part) {
  const int tid = threadIdx.x;
  const int lane = tid & 63, wave = tid >> 6;
  const int wr = wave >> 1, wc = wave & 1;   // wave grid 4m x 2n
  const int b = blockIdx.x;
  const int mt = b & 1;
  const int sk = (b >> 1) & 3;
  const int nt = b >> 3;                     // 0..31
  const int k0t = sk * (KC / 32);            // base k-tile index
  const int lrow = lane & 15, lkg = lane >> 4;

  const unsigned short* ab[2];
  const unsigned short* lb2[2];
#pragma unroll
  for (int mf = 0; mf < 2; ++mf) {
    const size_t t = (size_t)((mt * 8 + wr * 2 + mf) * 128 + k0t);
    ab[mf]  = xgh + (t << 9) + lane * 8;
    lb2[mf] = xgl + (t << 9) + lane * 8;
  }
  const unsigned short* zb[4];
#pragma unroll
  for (int nf = 0; nf < 4; ++nf)
    zb[nf] = z2 + (((size_t)((nt * 8 + wc * 4 + nf) * 128 + k0t)) << 6) + lane;

  f32x4 acc[2][4] = {};

  // prologue: load step 0 into current set
  bf16x8 cah[2], cal[2];
  unsigned int czw[4];
#pragma unroll
  for (int mf = 0; mf < 2; ++mf) {
    cah[mf] = *(const bf16x8*)(ab[mf]);
    cal[mf] = *(const bf16x8*)(lb2[mf]);
  }
#pragma unroll
  for (int nf = 0; nf < 4; ++nf) czw[nf] = zb[nf][0];

  for (int ks = 0; ks < KSTEPS; ++ks) {
    bf16x8 nah[2], nal[2];
    unsigned int nzw[4];
    if (ks + 1 < KSTEPS) {
#pragma unroll
      for (int mf = 0; mf < 2; ++mf) {
        nah[mf] = *(const bf16x8*)(ab[mf] + (size_t)(ks + 1) * 512);
        nal[mf] = *(const bf16x8*)(lb2[mf] + (size_t)(ks + 1) * 512);
      }
#pragma unroll
      for (int nf = 0; nf < 4; ++nf) nzw[nf] = zb[nf][(size_t)(ks + 1) * 64];
    } else {
#pragma unroll
      for (int mf = 0; mf < 2; ++mf) { nah[mf] = cah[mf]; nal[mf] = cal[mf]; }
#pragma unroll
      for (int nf = 0; nf < 4; ++nf) nzw[nf] = czw[nf];
    }

    bf16x8 bfr[4];
#pragma unroll
    for (int nf = 0; nf < 4; ++nf) bfr[nf] = zdec_pk(czw[nf]);

#pragma unroll
    for (int mf = 0; mf < 2; ++mf)
#pragma unroll
      for (int nf = 0; nf < 4; ++nf) {
        acc[mf][nf] = __builtin_amdgcn_mfma_f32_16x16x32_bf16(cah[mf], bfr[nf], acc[mf][nf], 0, 0, 0);
        acc[mf][nf] = __builtin_amdgcn_mfma_f32_16x16x32_bf16(cal[mf], bfr[nf], acc[mf][nf], 0, 0, 0);
      }

#pragma unroll
    for (int mf = 0; mf < 2; ++mf) { cah[mf] = nah[mf]; cal[mf] = nal[mf]; }
#pragma unroll
    for (int nf = 0; nf < 4; ++nf) czw[nf] = nzw[nf];
  }

  // C/D layout (m89-verified): col = lane&15, row = (lane>>4)*4 + reg
  float* pb = part + (size_t)sk * (M_ * N_);
#pragma unroll
  for (int mf = 0; mf < 2; ++mf)
#pragma unroll
    for (int nf = 0; nf < 4; ++nf)
#pragma unroll
      for (int r = 0; r < 4; ++r) {
        const int m = mt * BM + wr * 32 + mf * 16 + lkg * 4 + r;
        const int n = nt * BN + wc * 64 + nf * 16 + lrow;
        pb[(size_t)m * N_ + n] = acc[mf][nf][r];
      }
}

// ---------- K3: reduce 4 split-K partials + bias + LSQ epilogue (verified) ----------

__global__ __launch_bounds__(256) void k_epi(const float* __restrict__ part,
                                             const float* __restrict__ bias,
                                             const float* __restrict__ alpha,
                                             float* __restrict__ out) {
  const int i4 = blockIdx.x * 256 + threadIdx.x;  // over M_*N_/4
  const size_t off = (size_t)i4 * 4;
  const float4 p0 = *(const float4*)(part + off);
  const float4 p1 = *(const float4*)(part + (size_t)1 * M_ * N_ + off);
  const float4 p2 = *(const float4*)(part + (size_t)2 * M_ * N_ + off);
  const float4 p3 = *(const float4*)(part + (size_t)3 * M_ * N_ + off);
  const int n = (int)(off & (N_ - 1));
  const float4 bv = *(const float4*)(bias + n);
  const float a = fmaxf(alpha[0], 0.f) + 1e-8f;
  const float s = a / 127.0f;
  float4 o;
  o.x = lsq1(((p0.x + p1.x) + p2.x) + p3.x + bv.x, a, s);
  o.y = lsq1(((p0.y + p1.y) + p2.y) + p3.y + bv.y, a, s);
  o.z = lsq1(((p0.z + p1.z) + p2.z) + p3.z + bv.z, a, s);
  o.w = lsq1(((p0.w + p1.w) + p2.w) + p3.w + bv.w, a, s);
  *(float4*)(out + off) = o;
}

// ---------- launch ----------

extern "C" void kernel_launch(void* const* d_in, const int* in_sizes, int n_in,
                              void* d_out, int out_size, void* d_ws, size_t ws_size,
                              hipStream_t stream) {
  const float* x     = (const float*)d_in[0];
  const float* W     = (const float*)d_in[1];
  const float* bias  = (const float*)d_in[2];
  const float* theta = (const float*)d_in[3];
  const float* alpha = (const float*)d_in[4];
  const float* G     = (const float*)d_in[5];
  const float* Ginv  = (const float*)d_in[6];
  float* out = (float*)d_out;

  const int O = in_sizes[2];           // 4096
  const int kTheta = in_sizes[3] / O;  // 1

  // ws layout: xg_hi 2MB | xg_lo 2MB | z2 4MB | partials [4][M][N] 16MB
  char* ws = (char*)d_ws;
  unsigned short* xgh = (unsigned short*)ws;
  unsigned short* xgl = (unsigned short*)(ws + 2097152);
  unsigned short* z2  = (unsigned short*)(ws + 4194304);
  float* part = (float*)(ws + 8388608);
  if (ws_size < 25165824) return;  // guard: need 24MB scratch

  k_prep<<<NQB + NXB, 256, 0, stream>>>(W, theta, Ginv, x, G, z2, xgh, xgl, kTheta);
  k_gemm<<<2 * SPLITK * 32, 512, 0, stream>>>(xgh, xgl, z2, part);
  k_epi<<<(M_ * N_ / 4) / 256, 256, 0, stream>>>(part, bias, alpha, out);
}